// Round 3
// baseline (238.272 us; speedup 1.0000x reference)
//
#include <hip/hip_runtime.h>
#include <hip/hip_bf16.h>

// Conv 3x3 s1 p1, N=32 CIN=128 H=W=56 COUT=256, fp32 in/out, bf16 MFMA implicit GEMM.
//
// Plan:
//   ws layout: wt bf16 [9][256][128] at ws+0 (589,824 B)
//              xt bf16 [32][58][58][128] at ws+1MiB (27,557,888 B + 64 KiB slack)
//   1) memsetAsync xt (zero halo + slack)
//   2) k_wreorder: w OIHW fp32 -> wt [khkw][co][ci] bf16
//   3) k_xconv:    x NCHW fp32 -> xt NHWC-padded bf16 (LDS transpose tile)
//   4) k_conv_gemm: per block = one (n, oh) output row (56 px padded to 64) x all 256 couts.
//      K = 9 (khkw) x 128 (ci), BK=64. global_load_lds(16B) staging, T2 swizzle via
//      pre-swizzled global source (LDS dest must stay linear), swizzled ds_read_b128.

typedef __attribute__((ext_vector_type(8))) short bf16x8;
typedef __attribute__((ext_vector_type(4))) float f32x4;

#define AS1(p) ((const __attribute__((address_space(1))) unsigned int*)(p))
#define AS3(p) ((__attribute__((address_space(3))) unsigned int*)(p))
#define G_LDS16(g, l) __builtin_amdgcn_global_load_lds(AS1(g), AS3(l), 16, 0, 0)

#define WT_BYTES   (9 * 256 * 128 * 2)            // 589,824
#define XT_OFF     (1u << 20)
#define XT_ELEMS   (32 * 58 * 58 * 128)           // 13,778,944
#define XT_BYTES   (XT_ELEMS * 2)                 // 27,557,888
#define XT_SLACK   (1u << 16)

// ---- weight reorder: wt[(khkw*256+co)*128+ci] = w[(co*128+ci)*9+khkw] ----
__global__ __launch_bounds__(256) void k_wreorder(const float* __restrict__ w,
                                                  __hip_bfloat16* __restrict__ wt) {
    int t = blockIdx.x * 256 + threadIdx.x;     // 9*256*128 = 294,912 total
    if (t >= 9 * 256 * 128) return;
    int ci = t & 127;
    int co = (t >> 7) & 255;
    int khkw = t >> 15;
    wt[t] = __float2bfloat16(w[(co * 128 + ci) * 9 + khkw]);
}

// ---- x NCHW fp32 -> xt [n][ih=58][iw=58][ci=128] bf16 (interior only) ----
__global__ __launch_bounds__(256) void k_xconv(const float* __restrict__ x,
                                               __hip_bfloat16* __restrict__ xt) {
    int b = blockIdx.x;           // (n*56 + h) * 4 + ci_tile
    int ct = b & 3;
    int nh = b >> 2;
    int n = nh / 56, h = nh % 56;
    __shared__ float tile[56][33];            // [w][ci_local], pad to kill bank conflicts
    int t = threadIdx.x;
    for (int idx = t; idx < 32 * 56; idx += 256) {
        int cil = idx / 56, ww = idx % 56;    // coalesced along w
        tile[ww][cil] = x[((n * 128 + ct * 32 + cil) * 56 + h) * 56 + ww];
    }
    __syncthreads();
    int cil = t & 31, wset = t >> 5;
    for (int ww = wset; ww < 56; ww += 8) {   // writes coalesced along ci (64 B runs)
        xt[((n * 58 + h + 1) * 58 + ww + 1) * 128 + ct * 32 + cil] =
            __float2bfloat16(tile[ww][cil]);
    }
}

// ---- implicit GEMM ----
// block: (n, oh). tile 256 co x 64 px. 8 waves: wave>>1 -> co quadrant, wave&1 -> px half.
__global__ __launch_bounds__(512, 2) void k_conv_gemm(
    const __hip_bfloat16* __restrict__ wt,   // [9][256][128]
    const __hip_bfloat16* __restrict__ xt,   // [32][58][58][128] (+slack)
    const float* __restrict__ bias,          // [256]
    float* __restrict__ out)                 // [32][256][56][56]
{
    __shared__ char lds[256 * 64 * 2 + 64 * 64 * 2];   // A 32 KiB | B 8 KiB
    char* ldsA = lds;
    char* ldsB = lds + 256 * 64 * 2;

    // XCD-bijective swizzle: 1792 blocks = 8 * 224
    int bid = blockIdx.x;
    int blk = (bid & 7) * 224 + (bid >> 3);
    const int n = blk / 56, oh = blk % 56;

    const int tid = threadIdx.x;
    const int lane = tid & 63, wave = tid >> 6;
    const int co_w = (wave >> 1) * 64;       // wave's co base (0/64/128/192)
    const int px_w = (wave & 1) * 32;        // wave's px base (0/32)

    const int lr = lane >> 3;                // 0..7 : row within 8-row staging group
    const int lc = lane & 7;                 // 0..7 : 16B chunk within 128 B row
    const int swz = ((lc ^ lr) << 4);        // pre-swizzled source chunk (T2, rule #21)

    f32x4 acc[4][2] = {};

    for (int khkw = 0; khkw < 9; ++khkw) {
        const int kh = khkw / 3, kw = khkw % 3;
        const int xrowbase = ((n * 58 + oh + kh) * 58 + kw) * 128;  // elem idx @ px=0,ci=0
        for (int ci0 = 0; ci0 < 128; ci0 += 64) {
            // stage A: 256 rows x 128 B, 4 wave-rounds of 8 rows each
#pragma unroll
            for (int r = 0; r < 4; ++r) {
                int co = r * 64 + wave * 8 + lr;
                const char* src = (const char*)wt +
                    ((khkw * 256 + co) * 128 + ci0) * 2 + swz;
                G_LDS16(src, ldsA + (r * 64 + wave * 8) * 128);
            }
            // stage B: 64 px rows x 128 B, 1 wave-round
            {
                int px = wave * 8 + lr;
                const char* src = (const char*)xt +
                    (xrowbase + px * 128 + ci0) * 2 + swz;
                G_LDS16(src, ldsB + wave * 8 * 128);
            }
            __syncthreads();

            bf16x8 af[2][4], bx[2][2];
#pragma unroll
            for (int ks = 0; ks < 2; ++ks) {
#pragma unroll
                for (int m = 0; m < 4; ++m) {
                    int row = co_w + m * 16 + (lane & 15);
                    int koff = (ks * 64 + ((lane >> 4) * 16)) ^ ((row & 7) << 4);
                    af[ks][m] = *(const bf16x8*)(ldsA + row * 128 + koff);
                }
#pragma unroll
                for (int nn = 0; nn < 2; ++nn) {
                    int row = px_w + nn * 16 + (lane & 15);
                    int koff = (ks * 64 + ((lane >> 4) * 16)) ^ ((row & 7) << 4);
                    bx[ks][nn] = *(const bf16x8*)(ldsB + row * 128 + koff);
                }
            }
#pragma unroll
            for (int ks = 0; ks < 2; ++ks)
#pragma unroll
                for (int m = 0; m < 4; ++m)
#pragma unroll
                    for (int nn = 0; nn < 2; ++nn)
                        acc[m][nn] = __builtin_amdgcn_mfma_f32_16x16x32_bf16(
                            af[ks][m], bx[ks][nn], acc[m][nn], 0, 0, 0);
            __syncthreads();
        }
    }

    // epilogue: D row = co = (lane>>4)*4 + r (within 16), col = px = lane&15
    const int colpx = lane & 15;
    const int rgrp = lane >> 4;
#pragma unroll
    for (int m = 0; m < 4; ++m) {
#pragma unroll
        for (int r = 0; r < 4; ++r) {
            int co = co_w + m * 16 + rgrp * 4 + r;
            float bv = bias[co];
#pragma unroll
            for (int nn = 0; nn < 2; ++nn) {
                int ow = px_w + nn * 16 + colpx;
                if (ow < 56) {
                    out[(n * 256 + co) * 3136 + oh * 56 + ow] = acc[m][nn][r] + bv;
                }
            }
        }
    }
}

extern "C" void kernel_launch(void* const* d_in, const int* in_sizes, int n_in,
                              void* d_out, int out_size, void* d_ws, size_t ws_size,
                              hipStream_t stream) {
    const float* x    = (const float*)d_in[0];
    const float* w    = (const float*)d_in[1];
    const float* bias = (const float*)d_in[2];
    float* out = (float*)d_out;

    char* ws = (char*)d_ws;
    __hip_bfloat16* wt = (__hip_bfloat16*)ws;
    __hip_bfloat16* xt = (__hip_bfloat16*)(ws + XT_OFF);

    // zero halo + OOB slack (ws is re-poisoned 0xAA before every launch)
    hipMemsetAsync(xt, 0, XT_BYTES + XT_SLACK, stream);
    k_wreorder<<<(9 * 256 * 128 + 255) / 256, 256, 0, stream>>>(w, wt);
    k_xconv<<<32 * 56 * 4, 256, 0, stream>>>(x, xt);
    k_conv_gemm<<<32 * 56, 512, 0, stream>>>(wt, xt, bias, out);
}

// Round 4
// 206.538 us; speedup vs baseline: 1.1536x; 1.1536x over previous
//
#include <hip/hip_runtime.h>
#include <hip/hip_bf16.h>

// Conv 3x3 s1 p1, N=32 CIN=128 H=W=56 COUT=256, fp32 in/out, bf16 MFMA implicit GEMM.
// R4: (a) xconv rewritten — coalesced 16B stores, writes its own halo (memset dropped);
//     (b) gemm retiled 256co x 128px flat-pixel (no padded-px waste), same verified
//         2-barrier schedule + T2 swizzle (pre-swizzled source / swizzled ds_read).

typedef __attribute__((ext_vector_type(8))) short bf16x8;
typedef __attribute__((ext_vector_type(4))) float f32x4;
typedef __attribute__((ext_vector_type(8))) unsigned short u16x8;

#define AS1(p) ((const __attribute__((address_space(1))) unsigned int*)(p))
#define AS3(p) ((__attribute__((address_space(3))) unsigned int*)(p))
#define G_LDS16(g, l) __builtin_amdgcn_global_load_lds(AS1(g), AS3(l), 16, 0, 0)

#define XT_OFF (1u << 20)

// ---- weight reorder: wt[(khkw*256+co)*128+ci] = w[(co*128+ci)*9+khkw] ----
__global__ __launch_bounds__(256) void k_wreorder(const float* __restrict__ w,
                                                  __hip_bfloat16* __restrict__ wt) {
    int t = blockIdx.x * 256 + threadIdx.x;     // 9*256*128 = 294,912 total
    if (t >= 9 * 256 * 128) return;
    int ci = t & 127;
    int co = (t >> 7) & 255;
    int khkw = t >> 15;
    wt[t] = __float2bfloat16(w[(co * 128 + ci) * 9 + khkw]);
}

// ---- x NCHW fp32 -> xt [n][ih=58][iw=58][ci=128] bf16, halo included ----
// block = (n, ih). Interior: LDS transpose tile [w][ci]; writes one full xt row
// (58 px * 256 B = 14,848 B contiguous) with 16B stores. Border rows: zeros.
__global__ __launch_bounds__(256) void k_xconv(const float* __restrict__ x,
                                               __hip_bfloat16* __restrict__ xt) {
    const int b = blockIdx.x;                 // n*58 + ih
    const int n = b / 58, ih = b % 58;
    __hip_bfloat16* row = xt + (size_t)b * 58 * 128;
    const int t = threadIdx.x;

    if (ih == 0 || ih == 57) {                // top/bottom halo row: all zeros
        u16x8 z = {0, 0, 0, 0, 0, 0, 0, 0};
        for (int i = t; i < 928; i += 256)    // 58*128*2B / 16B
            ((u16x8*)row)[i] = z;
        return;
    }

    const int h = ih - 1;
    __shared__ float tile[56][132];           // [w][ci], stride 132 (528B, 16B-aligned)
    const float* xb = x + (size_t)n * 128 * 3136 + h * 56;
    for (int i = t; i < 1792; i += 256) {     // 128 ci-rows x 14 float4
        int ci = i / 14, w4 = i % 14;
        f32x4 v = *(const f32x4*)(xb + ci * 3136 + w4 * 4);
#pragma unroll
        for (int c = 0; c < 4; ++c)
            tile[w4 * 4 + c][ci] = v[c];
    }
    __syncthreads();

    if (t < 32) {                             // left/right halo columns: zeros
        u16x8 z = {0, 0, 0, 0, 0, 0, 0, 0};
        int iw = (t < 16) ? 0 : 57;
        ((u16x8*)(row + iw * 128))[t & 15] = z;
    }
    for (int i = t; i < 896; i += 256) {      // 56 px x 16 chunks, g-major (coalesced)
        int p = i >> 4, g = i & 15;
        u16x8 o;
#pragma unroll
        for (int j = 0; j < 8; ++j) {
            __hip_bfloat16 bv = __float2bfloat16(tile[p][g * 8 + j]);
            o[j] = *reinterpret_cast<unsigned short*>(&bv);
        }
        *(u16x8*)((char*)row + (p + 1) * 256 + g * 16) = o;
    }
}

// ---- implicit GEMM: tile 256 co x 128 px (flat pixels), K = 9*128, BK=64 ----
__global__ __launch_bounds__(512, 2) void k_conv_gemm(
    const __hip_bfloat16* __restrict__ wt,   // [9][256][128]
    const __hip_bfloat16* __restrict__ xt,   // [32][58][58][128]
    const float* __restrict__ bias,          // [256]
    float* __restrict__ out)                 // [32][256][56][56]
{
    __shared__ char lds[256 * 128 + 128 * 128];   // A 32 KiB | B 16 KiB
    char* ldsA = lds;
    char* ldsB = lds + 256 * 128;

    // XCD-bijective swizzle: 784 blocks = 8 * 98
    const int bid = blockIdx.x;
    const int blk = (bid & 7) * 98 + (bid >> 3);

    const int tid = threadIdx.x;
    const int lane = tid & 63, wave = tid >> 6;
    const int co_w = (wave >> 1) * 64;       // wave's co base (0/64/128/192)
    const int px_w = (wave & 1) * 64;        // wave's px base (0/64)

    const int lr = lane >> 3;                // staging row within 8-row group
    const int lc = lane & 7;                 // 16B chunk within 128B row
    const int swz = ((lc ^ lr) << 4);        // pre-swizzled source chunk (T2)

    // per-lane B-staging source bases (pixel geometry fixed across K-loop)
    unsigned int bsrc[2];
#pragma unroll
    for (int r = 0; r < 2; ++r) {
        int px = r * 64 + wave * 8 + lr;
        int p = blk * 128 + px;
        int n = p / 3136, rem = p - n * 3136;
        int oh = rem / 56, ow = rem - oh * 56;
        bsrc[r] = (unsigned)(((n * 58 + oh) * 58 + ow) * 256) + swz;
    }

    f32x4 acc[4][4] = {};

    for (int khkw = 0; khkw < 9; ++khkw) {
        const int kh = khkw / 3, kw = khkw - kh * 3;
        const unsigned koffB = (unsigned)((kh * 58 + kw) * 256);
        const unsigned aoff = (unsigned)(khkw * 65536);
        for (int ci2 = 0; ci2 < 256; ci2 += 128) {   // BK=64 ci -> 128 B
            // stage A: 256 rows x 128B, 4 wave-rounds of 8 rows
#pragma unroll
            for (int r = 0; r < 4; ++r) {
                int co = r * 64 + wave * 8 + lr;
                G_LDS16((const char*)wt + aoff + ci2 + co * 256 + swz,
                        ldsA + (r * 64 + wave * 8) * 128);
            }
            // stage B: 128 px rows x 128B, 2 wave-rounds (per-lane gather source)
#pragma unroll
            for (int r = 0; r < 2; ++r) {
                G_LDS16((const char*)xt + bsrc[r] + koffB + ci2,
                        ldsB + (r * 64 + wave * 8) * 128);
            }
            __syncthreads();

#pragma unroll
            for (int ks = 0; ks < 2; ++ks) {
                bf16x8 af[4], bx[4];
#pragma unroll
                for (int m = 0; m < 4; ++m) {
                    int row = co_w + m * 16 + (lane & 15);
                    int koff = (ks * 64 + ((lane >> 4) * 16)) ^ ((row & 7) << 4);
                    af[m] = *(const bf16x8*)(ldsA + row * 128 + koff);
                }
#pragma unroll
                for (int nn = 0; nn < 4; ++nn) {
                    int row = px_w + nn * 16 + (lane & 15);
                    int koff = (ks * 64 + ((lane >> 4) * 16)) ^ ((row & 7) << 4);
                    bx[nn] = *(const bf16x8*)(ldsB + row * 128 + koff);
                }
#pragma unroll
                for (int m = 0; m < 4; ++m)
#pragma unroll
                    for (int nn = 0; nn < 4; ++nn)
                        acc[m][nn] = __builtin_amdgcn_mfma_f32_16x16x32_bf16(
                            af[m], bx[nn], acc[m][nn], 0, 0, 0);
            }
            __syncthreads();
        }
    }

    // epilogue: D col = px = lane&15 (+nn*16+px_w), D row = co = (lane>>4)*4 + r
    int obase[4];
#pragma unroll
    for (int nn = 0; nn < 4; ++nn) {
        int p = blk * 128 + px_w + nn * 16 + (lane & 15);
        int n = p / 3136, rem = p - n * 3136;
        obase[nn] = n * 802816 + rem;        // + co*3136 gives out index
    }
    const int rgrp = lane >> 4;
#pragma unroll
    for (int m = 0; m < 4; ++m) {
#pragma unroll
        for (int r = 0; r < 4; ++r) {
            int co = co_w + m * 16 + rgrp * 4 + r;
            float bv = bias[co];
#pragma unroll
            for (int nn = 0; nn < 4; ++nn)
                out[obase[nn] + co * 3136] = acc[m][nn][r] + bv;
        }
    }
}

extern "C" void kernel_launch(void* const* d_in, const int* in_sizes, int n_in,
                              void* d_out, int out_size, void* d_ws, size_t ws_size,
                              hipStream_t stream) {
    const float* x    = (const float*)d_in[0];
    const float* w    = (const float*)d_in[1];
    const float* bias = (const float*)d_in[2];
    float* out = (float*)d_out;

    char* ws = (char*)d_ws;
    __hip_bfloat16* wt = (__hip_bfloat16*)ws;
    __hip_bfloat16* xt = (__hip_bfloat16*)(ws + XT_OFF);

    k_wreorder<<<1152, 256, 0, stream>>>(w, wt);
    k_xconv<<<32 * 58, 256, 0, stream>>>(x, xt);      // writes full xt incl. halo
    k_conv_gemm<<<784, 512, 0, stream>>>(wt, xt, bias, out);
}